// Round 5
// baseline (554.460 us; speedup 1.0000x reference)
//
#include <hip/hip_runtime.h>
#include <math.h>

constexpr int B = 4, C = 256, CC = 32, H = 64, W = 64, HW = H * W;
constexpr int G = 8, K = 9, GN = 32, CPG = C / GN;   // CPG = 8
constexpr int OFFC = 3 * G * K;                       // 216

typedef __attribute__((ext_vector_type(8))) short short8;
typedef __attribute__((ext_vector_type(4))) float f32x4;

__device__ inline short f2bf(float f) {
  unsigned u = __builtin_bit_cast(unsigned, f);
  return (short)((u + 0x7FFFu + ((u >> 16) & 1u)) >> 16);
}
__device__ inline float bf2f(short s) {
  unsigned u = ((unsigned)(unsigned short)s) << 16;
  return __builtin_bit_cast(float, u);
}

// ---------------- resize (2x2 avg pool: rate=2, align_corners=False) ---------
__global__ void k_resize(const float* __restrict__ in, float* __restrict__ out) {
  int idx = blockIdx.x * 256 + threadIdx.x;
  if (idx >= B * CC * HW) return;
  int p = idx & (HW - 1);
  int c = (idx / HW) % CC;
  int b = idx / (HW * CC);
  int y = p >> 6, x = p & 63;
  const float* src = in + ((size_t)b * CC + c) * (2 * H) * (2 * W);
  const float* r0 = src + (2 * y) * (2 * W) + 2 * x;
  const float* r1 = r0 + 2 * W;
  out[idx] = 0.25f * (r0[0] + r0[1] + r1[0] + r1[1]);
}

// ---------------- transpose+convert: fp32 [Csrc][HW] -> bf16 [HW][Cdst] ------
__global__ void k_transpose(const float* __restrict__ src, short* __restrict__ dst,
                            int Csrc, int Cdst, int coff) {
  int t = threadIdx.x;
  int p0 = blockIdx.x * 64;
  int cc0 = blockIdx.y * 32;
  int b = blockIdx.z;
  int px = t >> 2, cq = t & 3;
  const float* s = src + ((size_t)b * Csrc + cc0 + cq * 8) * HW + p0 + px;
  short8 v;
  #pragma unroll
  for (int j = 0; j < 8; ++j) v[j] = f2bf(s[(size_t)j * HW]);
  *(short8*)(dst + ((size_t)b * HW + p0 + px) * Cdst + coff + cc0 + cq * 8) = v;
}

// ---------------- weight transform: [Cout][Cin][T] fp32 -> [T][Cout][Cin] bf16
template<int TAPS>
__global__ void k_wt(const float* __restrict__ w, short* __restrict__ wT,
                     int Cout, int Cin) {
  int id = blockIdx.x * 256 + threadIdx.x;
  if (id >= Cout * Cin) return;
  if (TAPS == 1) {
    wT[id] = f2bf(w[id]);
  } else {
    int o = id / Cin, ci = id % Cin;
    #pragma unroll
    for (int k = 0; k < 9; ++k)
      wT[((size_t)k * Cout + o) * Cin + ci] = f2bf(w[(size_t)id * 9 + k]);
  }
}

// ---------------- MFMA implicit-GEMM conv (taps=1 or 9, pad=(taps==9)) -------
template<int CIN, int COUT, int TAPS>
__global__ __launch_bounds__(256) void k_mfma_conv(
    const short* __restrict__ gT, const short* __restrict__ wT,
    const float* __restrict__ bias, float* __restrict__ out) {
  constexpr int POS = (TAPS == 9) ? 4 * 66 : 128;   // staged positions
  constexpr int PSTR = 40;                          // u16 per position (80 B)
  __shared__ short lds[POS * PSTR];
  const int tid = threadIdx.x;
  const int lane = tid & 63, wv = tid >> 6;
  const int l15 = lane & 15, l4 = lane >> 4;
  const int b = blockIdx.z;
  const int o0 = blockIdx.y * 64;
  const int p0 = blockIdx.x * 128;
  const int y0 = p0 >> 6;                           // 2 image rows per block

  f32x4 acc[4][2];
  #pragma unroll
  for (int mt = 0; mt < 4; ++mt)
    #pragma unroll
    for (int nt = 0; nt < 2; ++nt) acc[mt][nt] = (f32x4)0.f;

  const short* gTb = gT + (size_t)b * HW * CIN;

  for (int ck = 0; ck < CIN / 32; ++ck) {
    const int ci0 = ck * 32;
    __syncthreads();
    for (int i = tid; i < POS * 4; i += 256) {
      int pos = i >> 2, cq = i & 3;
      short8 v = {0, 0, 0, 0, 0, 0, 0, 0};
      if (TAPS == 9) {
        int r = pos / 66;
        int cx = pos - r * 66 - 1;
        int y = y0 - 1 + r;
        if ((unsigned)y < (unsigned)H && (unsigned)cx < (unsigned)W)
          v = *(const short8*)(gTb + (size_t)(y * W + cx) * CIN + ci0 + cq * 8);
      } else {
        v = *(const short8*)(gTb + (size_t)(p0 + pos) * CIN + ci0 + cq * 8);
      }
      *(short8*)(lds + pos * PSTR + cq * 8) = v;
    }
    __syncthreads();

    for (int tap = 0; tap < TAPS; ++tap) {
      short8 a[4];
      #pragma unroll
      for (int mt = 0; mt < 4; ++mt) {
        int o_r = o0 + mt * 16 + l15;
        if (COUT % 64 == 0 || o_r < COUT)
          a[mt] = *(const short8*)(wT + ((size_t)tap * COUT + o_r) * CIN + ci0 + l4 * 8);
        else
          a[mt] = (short8){0, 0, 0, 0, 0, 0, 0, 0};
      }
      short8 bb[2];
      #pragma unroll
      for (int nt = 0; nt < 2; ++nt) {
        int pos;
        if (TAPS == 9) {
          int dy = tap / 3 - 1, dx = tap % 3 - 1;
          int row = (wv >> 1) + dy + 1;
          int col = (wv & 1) * 32 + nt * 16 + l15 + dx + 1;
          pos = row * 66 + col;
        } else {
          pos = wv * 32 + nt * 16 + l15;
        }
        bb[nt] = *(const short8*)(lds + pos * PSTR + l4 * 8);
      }
      #pragma unroll
      for (int mt = 0; mt < 4; ++mt)
        #pragma unroll
        for (int nt = 0; nt < 2; ++nt)
          acc[mt][nt] = __builtin_amdgcn_mfma_f32_16x16x32_bf16(
              a[mt], bb[nt], acc[mt][nt], 0, 0, 0);
    }
  }

  #pragma unroll
  for (int mt = 0; mt < 4; ++mt) {
    #pragma unroll
    for (int nt = 0; nt < 2; ++nt) {
      int p = p0 + wv * 32 + nt * 16 + l15;
      #pragma unroll
      for (int r = 0; r < 4; ++r) {
        int oo = o0 + mt * 16 + l4 * 4 + r;
        if (COUT % 64 == 0 || oo < COUT)
          out[((size_t)b * COUT + oo) * HW + p] = acc[mt][nt][r] + bias[oo];
      }
    }
  }
}

// ---------------- GroupNorm + SiLU (fp32 in-place variant, for gn1) ----------
__global__ void k_gn_silu(const float* __restrict__ in, float* __restrict__ out,
                          const float* __restrict__ gamma, const float* __restrict__ beta) {
  int g = blockIdx.x, b = blockIdx.y;
  const float* base = in + ((size_t)b * C + g * CPG) * HW;
  float s = 0.f, s2 = 0.f;
  for (int i = threadIdx.x; i < CPG * HW; i += 256) {
    float v = base[i]; s += v; s2 += v * v;
  }
  #pragma unroll
  for (int off = 32; off > 0; off >>= 1) {
    s  += __shfl_down(s, off);
    s2 += __shfl_down(s2, off);
  }
  __shared__ float sh[8];
  __shared__ float mi[2];
  int wid = threadIdx.x >> 6, lane = threadIdx.x & 63;
  if (lane == 0) { sh[wid] = s; sh[4 + wid] = s2; }
  __syncthreads();
  if (threadIdx.x == 0) {
    float ts = sh[0] + sh[1] + sh[2] + sh[3];
    float t2 = sh[4] + sh[5] + sh[6] + sh[7];
    float mean = ts * (1.f / (CPG * HW));
    float var  = t2 * (1.f / (CPG * HW)) - mean * mean;
    mi[0] = mean; mi[1] = rsqrtf(var + 1e-6f);
  }
  __syncthreads();
  float mean = mi[0], inv = mi[1];
  float* ob = out + ((size_t)b * C + g * CPG) * HW;
  for (int i = threadIdx.x; i < CPG * HW; i += 256) {
    int c = g * CPG + (i >> 12);
    float v = (base[i] - mean) * inv * gamma[c] + beta[c];
    ob[i] = v / (1.f + expf(-v));
  }
}

// ---------------- GN stats pass: mean + rsqrt(var) per (group, b) ------------
__global__ void k_gn_stats(const float* __restrict__ in, float2* __restrict__ stats) {
  int g = blockIdx.x, b = blockIdx.y;
  const float* base = in + ((size_t)b * C + g * CPG) * HW;
  float s = 0.f, s2 = 0.f;
  for (int i = threadIdx.x; i < CPG * HW; i += 256) {
    float v = base[i]; s += v; s2 += v * v;
  }
  #pragma unroll
  for (int off = 32; off > 0; off >>= 1) {
    s  += __shfl_down(s, off);
    s2 += __shfl_down(s2, off);
  }
  __shared__ float sh[8];
  int wid = threadIdx.x >> 6, lane = threadIdx.x & 63;
  if (lane == 0) { sh[wid] = s; sh[4 + wid] = s2; }
  __syncthreads();
  if (threadIdx.x == 0) {
    float ts = sh[0] + sh[1] + sh[2] + sh[3];
    float t2 = sh[4] + sh[5] + sh[6] + sh[7];
    float mean = ts * (1.f / (CPG * HW));
    float var  = t2 * (1.f / (CPG * HW)) - mean * mean;
    stats[b * GN + g] = make_float2(mean, rsqrtf(var + 1e-6f));
  }
}

// ------- GN apply + SiLU + transpose to bf16 [HW][C] (opt. fp32 out too) -----
template<int WRITE_F32>
__global__ void k_gnt(const float* __restrict__ in, const float2* __restrict__ stats,
                      const float* __restrict__ gamma, const float* __restrict__ beta,
                      short* __restrict__ T, float* __restrict__ outf) {
  int t = threadIdx.x;
  int p0 = blockIdx.x * 64;
  int b = blockIdx.y;
  int px = t >> 2, cq = t & 3;
  int p = p0 + px;
  #pragma unroll
  for (int cc0 = 0; cc0 < C; cc0 += 32) {
    int cbase = cc0 + cq * 8;
    float2 mi = stats[b * GN + (cbase >> 3)];
    short8 v;
    #pragma unroll
    for (int j = 0; j < 8; ++j) {
      int c = cbase + j;
      float x = in[((size_t)b * C + c) * HW + p];
      float y = (x - mi.x) * mi.y * gamma[c] + beta[c];
      y = y / (1.f + expf(-y));
      if (WRITE_F32) outf[((size_t)b * C + c) * HW + p] = y;
      v[j] = f2bf(y);
    }
    *(short8*)(T + ((size_t)b * HW + p) * C + cbase) = v;
  }
}

// ---------------- depthwise 7x7, pad 3 — 4 px per thread, float4 row loads ---
__global__ void k_dw7(const float* __restrict__ in, const float* __restrict__ w,
                      const float* __restrict__ bias, float* __restrict__ out) {
  int t = blockIdx.x * 256 + threadIdx.x;   // 0..1023 per (c,b)
  int c = blockIdx.y, b = blockIdx.z;
  int x4 = (t & 15) * 4;
  int y = t >> 4;
  const float* src = in + ((size_t)b * C + c) * HW;
  const float* wk = w + c * 49;
  float bz = bias[c];
  float a0 = bz, a1 = bz, a2 = bz, a3 = bz;
  const float4 z4 = make_float4(0.f, 0.f, 0.f, 0.f);
  #pragma unroll
  for (int ky = 0; ky < 7; ++ky) {
    int yy = y + ky - 3;
    if ((unsigned)yy >= (unsigned)H) continue;
    const float* row = src + yy * W;
    float4 A = (x4 >= 4)  ? *(const float4*)(row + x4 - 4) : z4;
    float4 Bm = *(const float4*)(row + x4);
    float4 Cx = (x4 <= 56) ? *(const float4*)(row + x4 + 4) : z4;
    float rb[12] = {A.x, A.y, A.z, A.w, Bm.x, Bm.y, Bm.z, Bm.w, Cx.x, Cx.y, Cx.z, Cx.w};
    #pragma unroll
    for (int kx = 0; kx < 7; ++kx) {
      float wv = wk[ky * 7 + kx];
      a0 += wv * rb[kx + 1];
      a1 += wv * rb[kx + 2];
      a2 += wv * rb[kx + 3];
      a3 += wv * rb[kx + 4];
    }
  }
  *(float4*)(out + ((size_t)b * C + c) * HW + y * W + x4) = make_float4(a0, a1, a2, a3);
}

// ---------------- modulated deformable conv 3x3 via MFMA (v4) ----------------
// 16-px tile, 256 threads (4 waves, one 64-out tile each), grid 1024 blocks
// = 4 independent blocks/CU for latency overlap across barrier phases.
__global__ __launch_bounds__(256) void k_deform_mfma(
    const short* __restrict__ xmT, const float* __restrict__ co,
    const short* __restrict__ wT, const float* __restrict__ bias,
    float* __restrict__ out) {
  constexpr int PSTR = 40;                  // u16 per pixel slot (80 B)
  __shared__ short s[9 * 16 * PSTR];        // 11520 B
  __shared__ float4 wgt[9][16];             // 2304 B
  __shared__ int4   ofs[9][16];             // 2304 B
  const int tid = threadIdx.x;
  const int lane = tid & 63, wv = tid >> 6;
  const int l15 = lane & 15, l4 = lane >> 4;
  const int b = blockIdx.y;
  const int p0 = blockIdx.x * 16;
  const int o0 = wv * 64;                   // wave's output-channel tile

  f32x4 acc[4];
  #pragma unroll
  for (int mt = 0; mt < 4; ++mt) acc[mt] = (f32x4)0.f;

  const short* xb = xmT + (size_t)b * HW * C;
  const float* cob = co + (size_t)b * OFFC * HW;

  for (int g = 0; g < G; ++g) {
    __syncthreads();
    // phase A: per-(tap,px) bilinear weights + clamped corner offsets
    if (tid < K * 16) {
      int k = tid >> 4, pl = tid & 15;
      int p = p0 + pl;
      float dy = cob[(size_t)((g * K + k) * 2) * HW + p];
      float dx = cob[(size_t)((g * K + k) * 2 + 1) * HW + p];
      float ml = cob[(size_t)(144 + g * K + k) * HW + p];
      float m = 1.f / (1.f + expf(-ml));
      int kh = k / 3 - 1, kw = k % 3 - 1;
      int py = p >> 6, px = p & 63;
      float yy = (float)(py + kh) + dy;
      float xx = (float)(px + kw) + dx;
      float yf = floorf(yy), xf = floorf(xx);
      float wy = yy - yf, wx = xx - xf;
      int y0 = (int)yf, x0 = (int)xf;
      bool yv0 = (unsigned)y0 < (unsigned)H, yv1 = (unsigned)(y0 + 1) < (unsigned)H;
      bool xv0 = (unsigned)x0 < (unsigned)W, xv1 = (unsigned)(x0 + 1) < (unsigned)W;
      int yc0 = min(max(y0, 0), H - 1), yc1 = min(max(y0 + 1, 0), H - 1);
      int xc0 = min(max(x0, 0), W - 1), xc1 = min(max(x0 + 1, 0), W - 1);
      float w00 = (yv0 && xv0) ? (1.f - wy) * (1.f - wx) * m : 0.f;
      float w01 = (yv0 && xv1) ? (1.f - wy) * wx * m : 0.f;
      float w10 = (yv1 && xv0) ? wy * (1.f - wx) * m : 0.f;
      float w11 = (yv1 && xv1) ? wy * wx * m : 0.f;
      wgt[k][pl] = make_float4(w00, w01, w10, w11);
      ofs[k][pl] = make_int4((yc0 * W + xc0) * C, (yc0 * W + xc1) * C,
                             (yc1 * W + xc0) * C, (yc1 * W + xc1) * C);
    }
    __syncthreads();
    // phase B: branch-free modulated bilinear staging (576 chunks)
    for (int i = tid; i < K * 16 * 4; i += 256) {
      int k = i >> 6, pl = (i >> 2) & 15, cq = i & 3;
      float4 ww = wgt[k][pl];
      int4 o4 = ofs[k][pl];
      const short* base = xb + g * 32 + cq * 8;
      short8 v00 = *(const short8*)(base + o4.x);
      short8 v01 = *(const short8*)(base + o4.y);
      short8 v10 = *(const short8*)(base + o4.z);
      short8 v11 = *(const short8*)(base + o4.w);
      short8 rr;
      #pragma unroll
      for (int j = 0; j < 8; ++j)
        rr[j] = f2bf(ww.x * bf2f(v00[j]) + ww.y * bf2f(v01[j]) +
                     ww.z * bf2f(v10[j]) + ww.w * bf2f(v11[j]));
      *(short8*)(s + (k * 16 + pl) * PSTR + cq * 8) = rr;
    }
    __syncthreads();
    // phase C: 9 taps x 4 MFMA per wave
    for (int k = 0; k < K; ++k) {
      short8 bb = *(const short8*)(s + (k * 16 + l15) * PSTR + l4 * 8);
      #pragma unroll
      for (int mt = 0; mt < 4; ++mt) {
        short8 a = *(const short8*)(wT + ((size_t)k * C + o0 + mt * 16 + l15) * C + g * 32 + l4 * 8);
        acc[mt] = __builtin_amdgcn_mfma_f32_16x16x32_bf16(a, bb, acc[mt], 0, 0, 0);
      }
    }
  }

  int p = p0 + l15;
  #pragma unroll
  for (int mt = 0; mt < 4; ++mt) {
    #pragma unroll
    for (int r = 0; r < 4; ++r) {
      int oo = o0 + mt * 16 + l4 * 4 + r;
      out[((size_t)b * C + oo) * HW + p] = acc[mt][r] + bias[oo];
    }
  }
}

extern "C" void kernel_launch(void* const* d_in, const int* in_sizes, int n_in,
                              void* d_out, int out_size, void* d_ws, size_t ws_size,
                              hipStream_t stream) {
  const float* x_main  = (const float*)d_in[0];
  const float* inpfeat = (const float*)d_in[1];
  const float* w1a = (const float*)d_in[2];
  const float* b1a = (const float*)d_in[3];
  const float* g1  = (const float*)d_in[4];
  const float* be1 = (const float*)d_in[5];
  const float* w1b = (const float*)d_in[6];
  const float* b1b = (const float*)d_in[7];
  const float* g2  = (const float*)d_in[8];
  const float* be2 = (const float*)d_in[9];
  const float* w1c = (const float*)d_in[10];
  const float* b1c = (const float*)d_in[11];
  const float* w2  = (const float*)d_in[12];
  const float* b2  = (const float*)d_in[13];
  const float* g3  = (const float*)d_in[14];
  const float* be3 = (const float*)d_in[15];
  const float* w_off = (const float*)d_in[16];
  const float* b_off = (const float*)d_in[17];
  const float* w_dcn = (const float*)d_in[18];
  const float* b_dcn = (const float*)d_in[19];

  float* warp_out = (float*)d_out;                      // output 0 [B,C,H,W]
  float* off_out  = warp_out + (size_t)B * C * HW;      // output 1 [B,C,H,W]

  // ---- workspace carve (bytes) ----
  char* ws = (char*)d_ws;
  float* r_inp = (float*)ws;                            //  2 MB [B][CC][HW]; later wTd
  float* fA    = (float*)(ws + (2u << 20));             // 16 MB [B][C][HW] (also co)
  short* T     = (short*)(ws + (2u << 20) + (16u << 20));   // 9.44 MB bf16 (also xmT)
  char*  wbase = ws + (2u << 20) + (16u << 20) + 9437184;
  short* wT1a  = (short*)(wbase);                       // 256*288
  short* wT1c  = (short*)(wbase + 294912);              // 256*256
  short* wT2   = (short*)(wbase + 294912 + 131072);     // 9*256*256
  short* wToff = (short*)(wbase + 294912 + 131072 + 1179648);  // 9*216*256
  float2* stats = (float2*)(wbase + 294912 + 131072 + 1179648 + 995328);  // 128 float2
  short* wTd   = (short*)r_inp;                         // 9*256*256 (after r_inp dead)
  float* fB = warp_out;   // scratch until final deform write
  float* co = fA;

  k_wt<1><<<dim3((256 * 288 + 255) / 256), 256, 0, stream>>>(w1a, wT1a, 256, 288);
  k_wt<1><<<dim3(256), 256, 0, stream>>>(w1c, wT1c, 256, 256);
  k_wt<9><<<dim3(256), 256, 0, stream>>>(w2, wT2, 256, 256);
  k_wt<9><<<dim3(216), 256, 0, stream>>>(w_off, wToff, 216, 256);

  k_resize<<<dim3((B * CC * HW) / 256), 256, 0, stream>>>(inpfeat, r_inp);
  k_transpose<<<dim3(HW / 64, 1, B), 256, 0, stream>>>(r_inp, T, CC, 288, 0);
  k_transpose<<<dim3(HW / 64, 8, B), 256, 0, stream>>>(x_main, T, C, 288, 32);
  k_mfma_conv<288, 256, 1><<<dim3(HW / 128, 4, B), 256, 0, stream>>>(T, wT1a, b1a, fA);
  k_wt<9><<<dim3(256), 256, 0, stream>>>(w_dcn, wTd, 256, 256);   // r_inp now dead
  k_gn_silu<<<dim3(GN, B), 256, 0, stream>>>(fA, fA, g1, be1);
  k_dw7<<<dim3(HW / 1024, C, B), 256, 0, stream>>>(fA, w1b, b1b, fB);
  // gn2 fused: stats + (apply + SiLU + bf16 transpose)
  k_gn_stats<<<dim3(GN, B), 256, 0, stream>>>(fB, stats);
  k_gnt<0><<<dim3(HW / 64, B), 256, 0, stream>>>(fB, stats, g2, be2, T, nullptr);
  k_mfma_conv<256, 256, 1><<<dim3(HW / 128, 4, B), 256, 0, stream>>>(T, wT1c, b1c, fA);
  k_transpose<<<dim3(HW / 64, 8, B), 256, 0, stream>>>(fA, T, C, 256, 0);
  k_mfma_conv<256, 256, 9><<<dim3(HW / 128, 4, B), 256, 0, stream>>>(T, wT2, b2, fB);
  // gn3 fused: stats + (apply + SiLU + fp32 off_out + bf16 transpose)
  k_gn_stats<<<dim3(GN, B), 256, 0, stream>>>(fB, stats);
  k_gnt<1><<<dim3(HW / 64, B), 256, 0, stream>>>(fB, stats, g3, be3, T, off_out);
  k_mfma_conv<256, 216, 9><<<dim3(HW / 128, 4, B), 256, 0, stream>>>(T, wToff, b_off, co);
  // T dead -> reuse as xmT [B][HW][256] bf16
  k_transpose<<<dim3(HW / 64, 8, B), 256, 0, stream>>>(x_main, T, C, 256, 0);
  k_deform_mfma<<<dim3(HW / 16, B), 256, 0, stream>>>(T, co, wTd, b_dcn, warp_out);
}